// Round 5
// baseline (157.180 us; speedup 1.0000x reference)
//
#include <hip/hip_runtime.h>
#include <hip/hip_bf16.h>
#include <float.h>

#define N 4096
#define DF 256
#define NBINS2 4096
#define MAXM 256

typedef __attribute__((ext_vector_type(8))) short short8v;
typedef __attribute__((ext_vector_type(8))) unsigned short ushort8v;
typedef __attribute__((ext_vector_type(4))) float floatx4;

__device__ inline unsigned short f2bf(float f) {
    __hip_bfloat16 h = __float2bfloat16(f);
    return *reinterpret_cast<unsigned short*>(&h);
}

__device__ inline void gload_lds16(const void* g, void* l) {
    __builtin_amdgcn_global_load_lds((const __attribute__((address_space(1))) void*)g,
                                     (__attribute__((address_space(3))) void*)l, 16, 0, 0);
}

// ---------------- prep: x2 norms + bf16 convert + (extra block) class bucketing ----------------
__global__ __launch_bounds__(256) void prep_kernel(const float* __restrict__ X,
                                                   const int* __restrict__ labels,
                                                   float* __restrict__ x2,
                                                   __hip_bfloat16* __restrict__ Xb,
                                                   int* __restrict__ cnt,
                                                   int* __restrict__ members,
                                                   double* __restrict__ accd,
                                                   int useXb) {
    int t = threadIdx.x;
    if (blockIdx.x == 1024) {
        // bucket block
        __shared__ int scnt[64];
        if (t < 8) accd[t] = 0.0;
        if (t < 64) scnt[t] = 0;
        __syncthreads();
        for (int i = t; i < N; i += 256) {
            int c = labels[i];
            int pos = atomicAdd(&scnt[c], 1);
            if (pos < MAXM) members[(c << 8) + pos] = i;
        }
        __syncthreads();
        if (t < 64) cnt[t] = min(scnt[t], MAXM);
        return;
    }
    int row = blockIdx.x * 4 + (t >> 6);
    int l = t & 63;
    int idx = row * 64 + l;
    float4 v = ((const float4*)X)[idx];
    if (useXb) {
        ushort4 o;
        o.x = f2bf(v.x); o.y = f2bf(v.y); o.z = f2bf(v.z); o.w = f2bf(v.w);
        ((ushort4*)Xb)[idx] = o;
    }
    float s = v.x * v.x + v.y * v.y + v.z * v.z + v.w * v.w;
#pragma unroll
    for (int off = 32; off > 0; off >>= 1) s += __shfl_xor(s, off, 64);
    if (l == 0) x2[row] = s;
}

// ---------------- per-class tiled 3-NN (16 queries x 64-member tiles, exact fp32) ----------------
__device__ inline void top3_upd(float& b0, float& b1, float& b2, float dd) {
    if (dd < b2) {
        if (dd < b1) { b2 = b1; if (dd < b0) { b1 = b0; b0 = dd; } else b1 = dd; }
        else b2 = dd;
    }
}

__global__ __launch_bounds__(256) void knn_class_kernel(const float* __restrict__ X,
                                                        const float* __restrict__ x2,
                                                        const int* __restrict__ cnt,
                                                        const int* __restrict__ members,
                                                        float* __restrict__ radii,
                                                        float* __restrict__ targetd,
                                                        double* __restrict__ accd) {
    __shared__ float A[16 * DF];        // queries, unswizzled (reads are broadcast)
    __shared__ float B[64 * DF];        // members, float4-index XOR-swizzled: [r*64 + (k4^r)]
    __shared__ int qidx[16];
    __shared__ float qx2[16];
    __shared__ int midx[64];
    __shared__ float mx2[64];

    int c = blockIdx.y;
    int qt = blockIdx.x;
    int m = cnt[c];
    if (qt * 16 >= m) return;
    const int* mem = members + (c << 8);
    int tid = threadIdx.x;
    int tx = tid & 31;
    int ty = tid >> 5;   // 0..7  -> queries ty and ty+8

    if (tid < 16) {
        int qq = qt * 16 + tid;
        int qi = (qq < m) ? mem[qq] : -1;
        qidx[tid] = qi;
        qx2[tid] = (qi >= 0) ? x2[qi] : 0.f;
    }
    __syncthreads();
#pragma unroll
    for (int cch = 0; cch < 4; ++cch) {
        int did = cch * 256 + tid;
        int r = did >> 6, k4 = did & 63;
        int qi = qidx[r];
        if (qi >= 0)
            ((float4*)A)[r * 64 + k4] = ((const float4*)(X + (size_t)qi * DF))[k4];
    }

    float b0a = FLT_MAX, b1a = FLT_MAX, b2a = FLT_MAX;
    float b0b = FLT_MAX, b1b = FLT_MAX, b2b = FLT_MAX;
    int j0 = tx, j1 = tx + 32;
    int nmt = (m + 63) >> 6;

    for (int mt = 0; mt < nmt; ++mt) {
        __syncthreads();   // protect midx/B from previous iteration's readers
        if (tid < 64) {
            int jj = mt * 64 + tid;
            int mi = (jj < m) ? mem[jj] : -1;
            midx[tid] = mi;
            mx2[tid] = (mi >= 0) ? x2[mi] : 0.f;
        }
        __syncthreads();
#pragma unroll
        for (int cch = 0; cch < 16; ++cch) {
            int did = cch * 256 + tid;
            int r = did >> 6, k4 = did & 63;
            int mi = midx[r];
            if (mi >= 0)
                ((float4*)B)[r * 64 + (k4 ^ r)] = ((const float4*)(X + (size_t)mi * DF))[k4];
        }
        __syncthreads();

        float4 d00 = {0.f, 0.f, 0.f, 0.f}, d01 = d00, d10 = d00, d11 = d00;
        const float4* A4 = (const float4*)A;
        const float4* B4 = (const float4*)B;
#pragma unroll 8
        for (int k4 = 0; k4 < 64; ++k4) {
            float4 a0 = A4[ty * 64 + k4];
            float4 a1 = A4[(ty + 8) * 64 + k4];
            float4 v0 = B4[j0 * 64 + (k4 ^ j0)];
            float4 v1 = B4[j1 * 64 + (k4 ^ j1)];
            d00.x += a0.x * v0.x; d00.y += a0.y * v0.y; d00.z += a0.z * v0.z; d00.w += a0.w * v0.w;
            d01.x += a0.x * v1.x; d01.y += a0.y * v1.y; d01.z += a0.z * v1.z; d01.w += a0.w * v1.w;
            d10.x += a1.x * v0.x; d10.y += a1.y * v0.y; d10.z += a1.z * v0.z; d10.w += a1.w * v0.w;
            d11.x += a1.x * v1.x; d11.y += a1.y * v1.y; d11.z += a1.z * v1.z; d11.w += a1.w * v1.w;
        }
        float s00 = (d00.x + d00.y) + (d00.z + d00.w);
        float s01 = (d01.x + d01.y) + (d01.z + d01.w);
        float s10 = (d10.x + d10.y) + (d10.z + d10.w);
        float s11 = (d11.x + d11.y) + (d11.z + d11.w);

        int qi0 = qidx[ty], qi1 = qidx[ty + 8];
        float q0x2 = qx2[ty], q1x2 = qx2[ty + 8];
        int mi0 = midx[j0], mi1 = midx[j1];
        float m0x2 = mx2[j0], m1x2 = mx2[j1];

        float dd;
        dd = (mi0 < 0 || mi0 == qi0) ? FLT_MAX : fmaxf(q0x2 + m0x2 - 2.f * s00, 0.f);
        top3_upd(b0a, b1a, b2a, dd);
        dd = (mi1 < 0 || mi1 == qi0) ? FLT_MAX : fmaxf(q0x2 + m1x2 - 2.f * s01, 0.f);
        top3_upd(b0a, b1a, b2a, dd);
        dd = (mi0 < 0 || mi0 == qi1) ? FLT_MAX : fmaxf(q1x2 + m0x2 - 2.f * s10, 0.f);
        top3_upd(b0b, b1b, b2b, dd);
        dd = (mi1 < 0 || mi1 == qi1) ? FLT_MAX : fmaxf(q1x2 + m1x2 - 2.f * s11, 0.f);
        top3_upd(b0b, b1b, b2b, dd);
    }

    // merge sorted triples across the 32 tx lanes (xor shuffles stay within 32-halves)
#pragma unroll
    for (int off = 1; off <= 16; off <<= 1) {
        float c0 = __shfl_xor(b0a, off, 64);
        float c1 = __shfl_xor(b1a, off, 64);
        float c2 = __shfl_xor(b2a, off, 64);
        float m0, m1, m2;
        if (b0a <= c0) {
            m0 = b0a;
            if (b1a <= c0) { m1 = b1a; m2 = fminf(b2a, c0); }
            else { m1 = c0; m2 = fminf(b1a, c1); }
        } else {
            m0 = c0;
            if (c1 <= b0a) { m1 = c1; m2 = fminf(c2, b0a); }
            else { m1 = b0a; m2 = fminf(c1, b1a); }
        }
        b0a = m0; b1a = m1; b2a = m2;

        c0 = __shfl_xor(b0b, off, 64);
        c1 = __shfl_xor(b1b, off, 64);
        c2 = __shfl_xor(b2b, off, 64);
        if (b0b <= c0) {
            m0 = b0b;
            if (b1b <= c0) { m1 = b1b; m2 = fminf(b2b, c0); }
            else { m1 = c0; m2 = fminf(b1b, c1); }
        } else {
            m0 = c0;
            if (c1 <= b0b) { m1 = c1; m2 = fminf(c2, b0b); }
            else { m1 = b0b; m2 = fminf(c1, b1b); }
        }
        b0b = m0; b1b = m1; b2b = m2;
    }

    if (tx == 0) {
        int i0 = qidx[ty];
        if (i0 >= 0) {
            targetd[3 * i0 + 0] = b0a;
            targetd[3 * i0 + 1] = b1a;
            targetd[3 * i0 + 2] = b2a;
            radii[i0] = 1.f + b2a;
            atomicAdd(&accd[0], (double)(b0a + b1a + b2a));
        }
        int i1 = qidx[ty + 8];
        if (i1 >= 0) {
            targetd[3 * i1 + 0] = b0b;
            targetd[3 * i1 + 1] = b1b;
            targetd[3 * i1 + 2] = b2b;
            radii[i1] = 1.f + b2b;
            atomicAdd(&accd[0], (double)(b0b + b1b + b2b));
        }
    }
}

// ---------------- counting sort + chord table + neighbor subtract ----------------
__device__ inline int bsearch_gt(const float* arr, float d) {
    int lo = 0, hi = N;
    while (lo < hi) {
        int mid = (lo + hi) >> 1;
        if (arr[mid] <= d) lo = mid + 1; else hi = mid;
    }
    return lo;
}

__global__ __launch_bounds__(1024) void sort_scan_kernel(const float* __restrict__ radii,
                                                         const float* __restrict__ targetd,
                                                         float2* __restrict__ ftab_g,
                                                         float* __restrict__ hdr,
                                                         double* __restrict__ accd) {
    __shared__ float t2[N];
    __shared__ int bcnt[N];
    __shared__ float fv[NBINS2 + 1];
    __shared__ float aux[64];
    __shared__ int iaux[16];
    int t = threadIdx.x;
    int wid = t >> 6, lane = t & 63;

    float4 vv = ((const float4*)radii)[t];
    float v0 = vv.x, v1 = vv.y, v2 = vv.z, v3 = vv.w;

    float mn = fminf(fminf(v0, v1), fminf(v2, v3));
    float mx = fmaxf(fmaxf(v0, v1), fmaxf(v2, v3));
#pragma unroll
    for (int off = 32; off > 0; off >>= 1) {
        mn = fminf(mn, __shfl_xor(mn, off, 64));
        mx = fmaxf(mx, __shfl_xor(mx, off, 64));
    }
    if (lane == 0) { aux[wid] = mn; aux[wid + 16] = mx; }
    bcnt[t] = 0; bcnt[t + 1024] = 0; bcnt[t + 2048] = 0; bcnt[t + 3072] = 0;
    __syncthreads();
    mn = aux[0]; mx = aux[16];
    for (int w = 1; w < 16; ++w) { mn = fminf(mn, aux[w]); mx = fmaxf(mx, aux[w + 16]); }
    float range = fmaxf(mx - mn, 1e-30f);
    float scale = (float)N / range * (1.f - 1e-6f);

    int b0i = max(0, min((int)((v0 - mn) * scale), N - 1));
    int b1i = max(0, min((int)((v1 - mn) * scale), N - 1));
    int b2i = max(0, min((int)((v2 - mn) * scale), N - 1));
    int b3i = max(0, min((int)((v3 - mn) * scale), N - 1));
    atomicAdd(&bcnt[b0i], 1); atomicAdd(&bcnt[b1i], 1);
    atomicAdd(&bcnt[b2i], 1); atomicAdd(&bcnt[b3i], 1);
    __syncthreads();

    int c0i = bcnt[4 * t], c1i = bcnt[4 * t + 1], c2i = bcnt[4 * t + 2], c3i = bcnt[4 * t + 3];
    int tot_i = c0i + c1i + c2i + c3i;
    int sc = tot_i;
#pragma unroll
    for (int off = 1; off < 64; off <<= 1) {
        int y = __shfl_up(sc, off, 64);
        if (lane >= off) sc += y;
    }
    if (lane == 63) iaux[wid] = sc;
    __syncthreads();
    if (t < 16) {
        int wv2 = iaux[t];
        int s = wv2;
#pragma unroll
        for (int off = 1; off < 16; off <<= 1) {
            int y = __shfl_up(s, off, 64);
            if (t >= off) s += y;
        }
        iaux[t] = s - wv2;
    }
    __syncthreads();
    int base = iaux[wid] + (sc - tot_i);
    int e0 = base, e1 = base + c0i, e2 = e1 + c1i, e3 = e2 + c2i;
    bcnt[4 * t] = e0; bcnt[4 * t + 1] = e1; bcnt[4 * t + 2] = e2; bcnt[4 * t + 3] = e3;
    __syncthreads();

    t2[atomicAdd(&bcnt[b0i], 1)] = v0;
    t2[atomicAdd(&bcnt[b1i], 1)] = v1;
    t2[atomicAdd(&bcnt[b2i], 1)] = v2;
    t2[atomicAdd(&bcnt[b3i], 1)] = v3;
    __syncthreads();

#pragma unroll
    for (int r = 0; r < 4; ++r) {
        int b = 4 * t + r;
        int st = b ? bcnt[b - 1] : 0;
        int en = bcnt[b];
        for (int a = st + 1; a < en; ++a) {
            float key = t2[a];
            int q = a - 1;
            while (q >= st && t2[q] > key) { t2[q + 1] = t2[q]; --q; }
            t2[q + 1] = key;
        }
    }
    __syncthreads();

    float w0 = t2[4 * t], w1 = t2[4 * t + 1], w2 = t2[4 * t + 2], w3 = t2[4 * t + 3];
    float tot4 = w0 + w1 + w2 + w3;
    float sfx = tot4;
#pragma unroll
    for (int off = 1; off < 64; off <<= 1) {
        float y = __shfl_down(sfx, off, 64);
        if (lane + off < 64) sfx += y;
    }
    if (lane == 0) aux[wid] = sfx;
    __syncthreads();
    if (t < 16) {
        float x = aux[t];
        float s = x;
#pragma unroll
        for (int off = 1; off < 16; off <<= 1) {
            float y = __shfl_down(s, off, 64);
            if (t + off < 16) s += y;
        }
        aux[t] = s - x;
    }
    __syncthreads();
    float after = aux[wid] + (sfx - tot4);
    float q3 = w3 + after, q2 = w2 + q3, q1 = w1 + q2, q0 = w0 + q1;
    float* ssf = (float*)bcnt;
    ssf[4 * t] = q0; ssf[4 * t + 1] = q1; ssf[4 * t + 2] = q2; ssf[4 * t + 3] = q3;
    __syncthreads();

    float d0 = t2[0], rmx2 = t2[N - 1];
    float wbin = fmaxf(rmx2 - d0, 1e-20f) / (float)NBINS2;
    for (int e = t; e <= NBINS2; e += 1024) {
        float x = d0 + wbin * (float)e;
        int lo = bsearch_gt(t2, x);
        float Sv = (lo < N) ? ssf[lo] : 0.f;
        fv[e] = Sv - x * (float)(N - lo);
    }
    __syncthreads();
    for (int b = t; b < NBINS2; b += 1024)
        ftab_g[b] = make_float2(fv[b], fv[b + 1] - fv[b]);
    if (t == 0) {
        hdr[0] = d0;
        hdr[1] = rmx2;
        hdr[2] = (float)NBINS2 / fmaxf(rmx2 - d0, 1e-20f);
        hdr[3] = ssf[0];
    }

    float loc = 0.f;
    for (int idx = t; idx < 3 * N; idx += 1024) {
        float d = targetd[idx];
        int lo = bsearch_gt(t2, d);
        if (lo < N) loc += ssf[lo] - d * (float)(N - lo);
    }
#pragma unroll
    for (int off = 32; off > 0; off >>= 1) loc += __shfl_xor(loc, off, 64);
    __syncthreads();
    if (lane == 0) aux[wid] = loc;
    __syncthreads();
    if (t == 0) {
        float s = 0.f;
        for (int w = 0; w < 16; ++w) s += aux[w];
        atomicAdd(&accd[2], (double)s);
    }
}

// ---------------- fused bf16 MFMA Gram + chord-table push epilogue ----------------
template<int USEXB>
__global__ __launch_bounds__(256) void push_gemm_kernel(const float* __restrict__ X,
                                                        const __hip_bfloat16* __restrict__ Xb,
                                                        const float* __restrict__ x2,
                                                        const float2* __restrict__ ftab_g,
                                                        const float* __restrict__ hdr,
                                                        double* __restrict__ accd) {
    __shared__ __align__(16) char smem[32768];
    __shared__ float x2r[128], x2c[128];
    __shared__ float red[256];

    int bid = blockIdx.x;
    int by = 0, rem = bid;
    while (rem >= 32 - by) { rem -= 32 - by; ++by; }
    int bx = by + rem;
    int rowBase = by * 128, colBase = bx * 128;

    int tid = threadIdx.x;
    int lane = tid & 63;
    int wv = tid >> 6;
    int wy = wv >> 1, wx = wv & 1;

    floatx4 acc4[4][4];
#pragma unroll
    for (int m = 0; m < 4; ++m)
#pragma unroll
        for (int n = 0; n < 4; ++n) acc4[m][n] = (floatx4){0.f, 0.f, 0.f, 0.f};

    if (tid < 128) { x2r[tid] = x2[rowBase + tid]; x2c[tid] = x2[colBase + tid]; }

    for (int k0 = 0; k0 < DF; k0 += 64) {
        if (k0) __syncthreads();
        if (USEXB) {
            const __hip_bfloat16* Ab = Xb + (size_t)rowBase * DF;
            const __hip_bfloat16* Bb = Xb + (size_t)colBase * DF;
#pragma unroll
            for (int i = 0; i < 4; ++i) {
                int did = wv * 256 + i * 64 + lane;
                int row = ((did >> 7) << 4) | (did & 15);
                int kb = (did >> 4) & 7;
                size_t goff = (size_t)row * DF + k0 + kb * 8;
                char* ldsA = smem + (size_t)(wv * 256 + i * 64) * 16;
                gload_lds16(Ab + goff, ldsA);
                gload_lds16(Bb + goff, ldsA + 16384);
            }
        } else {
#pragma unroll
            for (int cch = 0; cch < 4; ++cch) {
                int did = tid + (cch << 8);
                int row = ((did >> 7) << 4) | (did & 15);
                int kb = (did >> 4) & 7;
                const float* srcA = X + (size_t)(rowBase + row) * DF + k0 + kb * 8;
                const float* srcB = X + (size_t)(colBase + row) * DF + k0 + kb * 8;
                float4 a0 = *(const float4*)srcA;
                float4 a1 = *(const float4*)(srcA + 4);
                float4 e0 = *(const float4*)srcB;
                float4 e1 = *(const float4*)(srcB + 4);
                ushort8v va, vb;
                va[0] = f2bf(a0.x); va[1] = f2bf(a0.y); va[2] = f2bf(a0.z); va[3] = f2bf(a0.w);
                va[4] = f2bf(a1.x); va[5] = f2bf(a1.y); va[6] = f2bf(a1.z); va[7] = f2bf(a1.w);
                vb[0] = f2bf(e0.x); vb[1] = f2bf(e0.y); vb[2] = f2bf(e0.z); vb[3] = f2bf(e0.w);
                vb[4] = f2bf(e1.x); vb[5] = f2bf(e1.y); vb[6] = f2bf(e1.z); vb[7] = f2bf(e1.w);
                *((ushort8v*)(smem + (did << 4))) = va;
                *((ushort8v*)(smem + 16384 + (did << 4))) = vb;
            }
        }
        __syncthreads();
#pragma unroll
        for (int kk = 0; kk < 2; ++kk) {
            short8v a[4], b[4];
#pragma unroll
            for (int m = 0; m < 4; ++m)
                a[m] = *((const short8v*)(smem + (((wy * 4 + m) * 2 + kk) << 10) + (lane << 4)));
#pragma unroll
            for (int n = 0; n < 4; ++n)
                b[n] = *((const short8v*)(smem + 16384 + (((wx * 4 + n) * 2 + kk) << 10) + (lane << 4)));
#pragma unroll
            for (int m = 0; m < 4; ++m)
#pragma unroll
                for (int n = 0; n < 4; ++n)
                    acc4[m][n] = __builtin_amdgcn_mfma_f32_16x16x32_bf16(a[m], b[n], acc4[m][n], 0, 0, 0);
        }
    }
    __syncthreads();

    float4* ft4 = (float4*)smem;
    for (int i = tid; i < 2048; i += 256) ft4[i] = ((const float4*)ftab_g)[i];
    __syncthreads();
    const float2* ftab = (const float2*)smem;
    float d0v = hdr[0], rmaxv = hdr[1], invw = hdr[2], Stot = hdr[3];
    bool diag = (by == bx);

    float local = 0.f;
    int g = lane >> 4;
    int cl = lane & 15;
#pragma unroll
    for (int m = 0; m < 4; ++m) {
#pragma unroll
        for (int n = 0; n < 4; ++n) {
            floatx4 v = acc4[m][n];
            int gcl = wx * 64 + n * 16 + cl;
            float x2cv = x2c[gcl];
#pragma unroll
            for (int r = 0; r < 4; ++r) {
                int grl = wy * 64 + m * 16 + g * 4 + r;
                if (diag && grl == gcl) continue;
                float d = fmaxf(x2r[grl] + x2cv - 2.f * v[r], 0.f);
                if (d >= rmaxv) continue;
                if (d < d0v) {
                    local += fmaf(-d, (float)N, Stot);
                } else {
                    float tpos = (d - d0v) * invw;
                    int b = min((int)tpos, NBINS2 - 1);
                    float frac = tpos - (float)b;
                    float2 ab = ftab[b];
                    local += fmaf(frac, ab.y, ab.x);
                }
            }
        }
    }
    red[tid] = local;
    __syncthreads();
    for (int s2 = 128; s2 > 0; s2 >>= 1) {
        if (tid < s2) red[tid] += red[tid + s2];
        __syncthreads();
    }
    if (tid == 0) {
        float wt = diag ? 1.f : 2.f;
        atomicAdd(&accd[1], (double)(wt * red[0]));
    }
}

// ---------------- finalize ----------------
__global__ void finalize_kernel(const double* __restrict__ accd, float* __restrict__ out) {
    out[0] = (float)((accd[0] + accd[1] - accd[2]) / (double)N);
}

extern "C" void kernel_launch(void* const* d_in, const int* in_sizes, int n_in,
                              void* d_out, int out_size, void* d_ws, size_t ws_size,
                              hipStream_t stream) {
    const float* X = (const float*)d_in[0];
    const int* labels = (const int*)d_in[1];
    float* out = (float*)d_out;

    char* w = (char*)d_ws;
    double* accd   = (double*)w;                        // 64 B
    float* x2      = (float*)(w + 64);                  // 16 KB
    float* radii   = (float*)(w + 64 + 16384);          // 16 KB
    float* targetd = (float*)(w + 64 + 32768);          // 48 KB
    int* cnt       = (int*)(w + 64 + 81920);            // 256 B
    int* members   = (int*)(w + 64 + 82176);            // 64 KB
    float* hdr     = (float*)(w + 64 + 147712);         // 64 B
    float2* ftab_g = (float2*)(w + 64 + 147776);        // 32 KB
    __hip_bfloat16* Xb = (__hip_bfloat16*)(w + 64 + 180544); // 2 MB
    size_t need_xb = 64 + 180544 + (size_t)N * DF * 2;
    int useXb = (ws_size >= need_xb) ? 1 : 0;

    hipLaunchKernelGGL(prep_kernel, dim3(1025), dim3(256), 0, stream,
                       X, labels, x2, Xb, cnt, members, accd, useXb);
    hipLaunchKernelGGL(knn_class_kernel, dim3(16, 64), dim3(256), 0, stream,
                       X, x2, cnt, members, radii, targetd, accd);
    hipLaunchKernelGGL(sort_scan_kernel, dim3(1), dim3(1024), 0, stream,
                       radii, targetd, ftab_g, hdr, accd);
    if (useXb)
        hipLaunchKernelGGL(push_gemm_kernel<1>, dim3(528), dim3(256), 0, stream,
                           X, Xb, x2, ftab_g, hdr, accd);
    else
        hipLaunchKernelGGL(push_gemm_kernel<0>, dim3(528), dim3(256), 0, stream,
                           X, Xb, x2, ftab_g, hdr, accd);
    hipLaunchKernelGGL(finalize_kernel, dim3(1), dim3(1), 0, stream, accd, out);
}

// Round 6
// 153.742 us; speedup vs baseline: 1.0224x; 1.0224x over previous
//
#include <hip/hip_runtime.h>
#include <hip/hip_bf16.h>
#include <float.h>

#define N 4096
#define DF 256
#define NBINS2 4096
#define MAXM 256
#define NPUSHBLK 528

typedef __attribute__((ext_vector_type(8))) short short8v;
typedef __attribute__((ext_vector_type(8))) unsigned short ushort8v;
typedef __attribute__((ext_vector_type(4))) float floatx4;

__device__ inline unsigned short f2bf(float f) {
    __hip_bfloat16 h = __float2bfloat16(f);
    return *reinterpret_cast<unsigned short*>(&h);
}

__device__ inline void gload_lds16(const void* g, void* l) {
    __builtin_amdgcn_global_load_lds((const __attribute__((address_space(1))) void*)g,
                                     (__attribute__((address_space(3))) void*)l, 16, 0, 0);
}

// ---------------- prep: x2 norms + bf16 convert + (extra block) class bucketing ----------------
__global__ __launch_bounds__(256) void prep_kernel(const float* __restrict__ X,
                                                   const int* __restrict__ labels,
                                                   float* __restrict__ x2,
                                                   __hip_bfloat16* __restrict__ Xb,
                                                   int* __restrict__ cnt,
                                                   int* __restrict__ members,
                                                   double* __restrict__ accd,
                                                   int useXb) {
    int t = threadIdx.x;
    if (blockIdx.x == 1024) {
        __shared__ int scnt[64];
        if (t < 8) accd[t] = 0.0;
        if (t < 64) scnt[t] = 0;
        __syncthreads();
        for (int i = t; i < N; i += 256) {
            int c = labels[i];
            int pos = atomicAdd(&scnt[c], 1);
            if (pos < MAXM) members[(c << 8) + pos] = i;
        }
        __syncthreads();
        if (t < 64) cnt[t] = min(scnt[t], MAXM);
        return;
    }
    int row = blockIdx.x * 4 + (t >> 6);
    int l = t & 63;
    int idx = row * 64 + l;
    float4 v = ((const float4*)X)[idx];
    if (useXb) {
        ushort4 o;
        o.x = f2bf(v.x); o.y = f2bf(v.y); o.z = f2bf(v.z); o.w = f2bf(v.w);
        ((ushort4*)Xb)[idx] = o;
    }
    float s = v.x * v.x + v.y * v.y + v.z * v.z + v.w * v.w;
#pragma unroll
    for (int off = 32; off > 0; off >>= 1) s += __shfl_xor(s, off, 64);
    if (l == 0) x2[row] = s;
}

// ---------------- per-class tiled 3-NN (no atomics) ----------------
__device__ inline void top3_upd(float& b0, float& b1, float& b2, float dd) {
    if (dd < b2) {
        if (dd < b1) { b2 = b1; if (dd < b0) { b1 = b0; b0 = dd; } else b1 = dd; }
        else b2 = dd;
    }
}

__global__ __launch_bounds__(256) void knn_class_kernel(const float* __restrict__ X,
                                                        const float* __restrict__ x2,
                                                        const int* __restrict__ cnt,
                                                        const int* __restrict__ members,
                                                        float* __restrict__ radii,
                                                        float* __restrict__ targetd) {
    __shared__ float A[16 * DF];
    __shared__ float B[64 * DF];
    __shared__ int qidx[16];
    __shared__ float qx2[16];
    __shared__ int midx[64];
    __shared__ float mx2[64];

    int c = blockIdx.y;
    int qt = blockIdx.x;
    int m = cnt[c];
    if (qt * 16 >= m) return;
    const int* mem = members + (c << 8);
    int tid = threadIdx.x;
    int tx = tid & 31;
    int ty = tid >> 5;

    if (tid < 16) {
        int qq = qt * 16 + tid;
        int qi = (qq < m) ? mem[qq] : -1;
        qidx[tid] = qi;
        qx2[tid] = (qi >= 0) ? x2[qi] : 0.f;
    }
    __syncthreads();
#pragma unroll
    for (int cch = 0; cch < 4; ++cch) {
        int did = cch * 256 + tid;
        int r = did >> 6, k4 = did & 63;
        int qi = qidx[r];
        if (qi >= 0)
            ((float4*)A)[r * 64 + k4] = ((const float4*)(X + (size_t)qi * DF))[k4];
    }

    float b0a = FLT_MAX, b1a = FLT_MAX, b2a = FLT_MAX;
    float b0b = FLT_MAX, b1b = FLT_MAX, b2b = FLT_MAX;
    int j0 = tx, j1 = tx + 32;
    int nmt = (m + 63) >> 6;

    for (int mt = 0; mt < nmt; ++mt) {
        __syncthreads();
        if (tid < 64) {
            int jj = mt * 64 + tid;
            int mi = (jj < m) ? mem[jj] : -1;
            midx[tid] = mi;
            mx2[tid] = (mi >= 0) ? x2[mi] : 0.f;
        }
        __syncthreads();
#pragma unroll
        for (int cch = 0; cch < 16; ++cch) {
            int did = cch * 256 + tid;
            int r = did >> 6, k4 = did & 63;
            int mi = midx[r];
            if (mi >= 0)
                ((float4*)B)[r * 64 + (k4 ^ r)] = ((const float4*)(X + (size_t)mi * DF))[k4];
        }
        __syncthreads();

        float4 d00 = {0.f, 0.f, 0.f, 0.f}, d01 = d00, d10 = d00, d11 = d00;
        const float4* A4 = (const float4*)A;
        const float4* B4 = (const float4*)B;
#pragma unroll 8
        for (int k4 = 0; k4 < 64; ++k4) {
            float4 a0 = A4[ty * 64 + k4];
            float4 a1 = A4[(ty + 8) * 64 + k4];
            float4 v0 = B4[j0 * 64 + (k4 ^ j0)];
            float4 v1 = B4[j1 * 64 + (k4 ^ j1)];
            d00.x += a0.x * v0.x; d00.y += a0.y * v0.y; d00.z += a0.z * v0.z; d00.w += a0.w * v0.w;
            d01.x += a0.x * v1.x; d01.y += a0.y * v1.y; d01.z += a0.z * v1.z; d01.w += a0.w * v1.w;
            d10.x += a1.x * v0.x; d10.y += a1.y * v0.y; d10.z += a1.z * v0.z; d10.w += a1.w * v0.w;
            d11.x += a1.x * v1.x; d11.y += a1.y * v1.y; d11.z += a1.z * v1.z; d11.w += a1.w * v1.w;
        }
        float s00 = (d00.x + d00.y) + (d00.z + d00.w);
        float s01 = (d01.x + d01.y) + (d01.z + d01.w);
        float s10 = (d10.x + d10.y) + (d10.z + d10.w);
        float s11 = (d11.x + d11.y) + (d11.z + d11.w);

        int qi0 = qidx[ty], qi1 = qidx[ty + 8];
        float q0x2 = qx2[ty], q1x2 = qx2[ty + 8];
        int mi0 = midx[j0], mi1 = midx[j1];
        float m0x2 = mx2[j0], m1x2 = mx2[j1];

        float dd;
        dd = (mi0 < 0 || mi0 == qi0) ? FLT_MAX : fmaxf(q0x2 + m0x2 - 2.f * s00, 0.f);
        top3_upd(b0a, b1a, b2a, dd);
        dd = (mi1 < 0 || mi1 == qi0) ? FLT_MAX : fmaxf(q0x2 + m1x2 - 2.f * s01, 0.f);
        top3_upd(b0a, b1a, b2a, dd);
        dd = (mi0 < 0 || mi0 == qi1) ? FLT_MAX : fmaxf(q1x2 + m0x2 - 2.f * s10, 0.f);
        top3_upd(b0b, b1b, b2b, dd);
        dd = (mi1 < 0 || mi1 == qi1) ? FLT_MAX : fmaxf(q1x2 + m1x2 - 2.f * s11, 0.f);
        top3_upd(b0b, b1b, b2b, dd);
    }

#pragma unroll
    for (int off = 1; off <= 16; off <<= 1) {
        float c0 = __shfl_xor(b0a, off, 64);
        float c1 = __shfl_xor(b1a, off, 64);
        float c2 = __shfl_xor(b2a, off, 64);
        float m0, m1, m2;
        if (b0a <= c0) {
            m0 = b0a;
            if (b1a <= c0) { m1 = b1a; m2 = fminf(b2a, c0); }
            else { m1 = c0; m2 = fminf(b1a, c1); }
        } else {
            m0 = c0;
            if (c1 <= b0a) { m1 = c1; m2 = fminf(c2, b0a); }
            else { m1 = b0a; m2 = fminf(c1, b1a); }
        }
        b0a = m0; b1a = m1; b2a = m2;

        c0 = __shfl_xor(b0b, off, 64);
        c1 = __shfl_xor(b1b, off, 64);
        c2 = __shfl_xor(b2b, off, 64);
        if (b0b <= c0) {
            m0 = b0b;
            if (b1b <= c0) { m1 = b1b; m2 = fminf(b2b, c0); }
            else { m1 = c0; m2 = fminf(b1b, c1); }
        } else {
            m0 = c0;
            if (c1 <= b0b) { m1 = c1; m2 = fminf(c2, b0b); }
            else { m1 = b0b; m2 = fminf(c1, b1b); }
        }
        b0b = m0; b1b = m1; b2b = m2;
    }

    if (tx == 0) {
        int i0 = qidx[ty];
        if (i0 >= 0) {
            targetd[3 * i0 + 0] = b0a;
            targetd[3 * i0 + 1] = b1a;
            targetd[3 * i0 + 2] = b2a;
            radii[i0] = 1.f + b2a;
        }
        int i1 = qidx[ty + 8];
        if (i1 >= 0) {
            targetd[3 * i1 + 0] = b0b;
            targetd[3 * i1 + 1] = b1b;
            targetd[3 * i1 + 2] = b2b;
            radii[i1] = 1.f + b2b;
        }
    }
}

// ---------------- counting sort + chord table + pull + neighbor subtract ----------------
__device__ inline int bsearch_gt(const float* arr, float d) {
    int lo = 0, hi = N;
    while (lo < hi) {
        int mid = (lo + hi) >> 1;
        if (arr[mid] <= d) lo = mid + 1; else hi = mid;
    }
    return lo;
}

__global__ __launch_bounds__(1024) void sort_scan_kernel(const float* __restrict__ radii,
                                                         const float* __restrict__ targetd,
                                                         float2* __restrict__ ftab_g,
                                                         float* __restrict__ hdr,
                                                         double* __restrict__ accd) {
    __shared__ float t2[N];
    __shared__ int bcnt[N];
    __shared__ float fv[NBINS2 + 1];
    __shared__ float aux[64];
    __shared__ int iaux[16];
    int t = threadIdx.x;
    int wid = t >> 6, lane = t & 63;

    float4 vv = ((const float4*)radii)[t];
    float v0 = vv.x, v1 = vv.y, v2 = vv.z, v3 = vv.w;

    float mn = fminf(fminf(v0, v1), fminf(v2, v3));
    float mx = fmaxf(fmaxf(v0, v1), fmaxf(v2, v3));
#pragma unroll
    for (int off = 32; off > 0; off >>= 1) {
        mn = fminf(mn, __shfl_xor(mn, off, 64));
        mx = fmaxf(mx, __shfl_xor(mx, off, 64));
    }
    if (lane == 0) { aux[wid] = mn; aux[wid + 16] = mx; }
    bcnt[t] = 0; bcnt[t + 1024] = 0; bcnt[t + 2048] = 0; bcnt[t + 3072] = 0;
    __syncthreads();
    mn = aux[0]; mx = aux[16];
    for (int w = 1; w < 16; ++w) { mn = fminf(mn, aux[w]); mx = fmaxf(mx, aux[w + 16]); }
    float range = fmaxf(mx - mn, 1e-30f);
    float scale = (float)N / range * (1.f - 1e-6f);

    int b0i = max(0, min((int)((v0 - mn) * scale), N - 1));
    int b1i = max(0, min((int)((v1 - mn) * scale), N - 1));
    int b2i = max(0, min((int)((v2 - mn) * scale), N - 1));
    int b3i = max(0, min((int)((v3 - mn) * scale), N - 1));
    atomicAdd(&bcnt[b0i], 1); atomicAdd(&bcnt[b1i], 1);
    atomicAdd(&bcnt[b2i], 1); atomicAdd(&bcnt[b3i], 1);
    __syncthreads();

    int c0i = bcnt[4 * t], c1i = bcnt[4 * t + 1], c2i = bcnt[4 * t + 2], c3i = bcnt[4 * t + 3];
    int tot_i = c0i + c1i + c2i + c3i;
    int sc = tot_i;
#pragma unroll
    for (int off = 1; off < 64; off <<= 1) {
        int y = __shfl_up(sc, off, 64);
        if (lane >= off) sc += y;
    }
    if (lane == 63) iaux[wid] = sc;
    __syncthreads();
    if (t < 16) {
        int wv2 = iaux[t];
        int s = wv2;
#pragma unroll
        for (int off = 1; off < 16; off <<= 1) {
            int y = __shfl_up(s, off, 64);
            if (t >= off) s += y;
        }
        iaux[t] = s - wv2;
    }
    __syncthreads();
    int base = iaux[wid] + (sc - tot_i);
    int e0 = base, e1 = base + c0i, e2 = e1 + c1i, e3 = e2 + c2i;
    bcnt[4 * t] = e0; bcnt[4 * t + 1] = e1; bcnt[4 * t + 2] = e2; bcnt[4 * t + 3] = e3;
    __syncthreads();

    t2[atomicAdd(&bcnt[b0i], 1)] = v0;
    t2[atomicAdd(&bcnt[b1i], 1)] = v1;
    t2[atomicAdd(&bcnt[b2i], 1)] = v2;
    t2[atomicAdd(&bcnt[b3i], 1)] = v3;
    __syncthreads();

#pragma unroll
    for (int r = 0; r < 4; ++r) {
        int b = 4 * t + r;
        int st = b ? bcnt[b - 1] : 0;
        int en = bcnt[b];
        for (int a = st + 1; a < en; ++a) {
            float key = t2[a];
            int q = a - 1;
            while (q >= st && t2[q] > key) { t2[q + 1] = t2[q]; --q; }
            t2[q + 1] = key;
        }
    }
    __syncthreads();

    float w0 = t2[4 * t], w1 = t2[4 * t + 1], w2 = t2[4 * t + 2], w3 = t2[4 * t + 3];
    float tot4 = w0 + w1 + w2 + w3;
    float sfx = tot4;
#pragma unroll
    for (int off = 1; off < 64; off <<= 1) {
        float y = __shfl_down(sfx, off, 64);
        if (lane + off < 64) sfx += y;
    }
    if (lane == 0) aux[wid] = sfx;
    __syncthreads();
    if (t < 16) {
        float x = aux[t];
        float s = x;
#pragma unroll
        for (int off = 1; off < 16; off <<= 1) {
            float y = __shfl_down(s, off, 64);
            if (t + off < 16) s += y;
        }
        aux[t] = s - x;
    }
    __syncthreads();
    float after = aux[wid] + (sfx - tot4);
    float q3 = w3 + after, q2 = w2 + q3, q1 = w1 + q2, q0 = w0 + q1;
    float* ssf = (float*)bcnt;
    ssf[4 * t] = q0; ssf[4 * t + 1] = q1; ssf[4 * t + 2] = q2; ssf[4 * t + 3] = q3;
    __syncthreads();

    float d0 = t2[0], rmx2 = t2[N - 1];
    float wbin = fmaxf(rmx2 - d0, 1e-20f) / (float)NBINS2;
    for (int e = t; e <= NBINS2; e += 1024) {
        float x = d0 + wbin * (float)e;
        int lo = bsearch_gt(t2, x);
        float Sv = (lo < N) ? ssf[lo] : 0.f;
        fv[e] = Sv - x * (float)(N - lo);
    }
    __syncthreads();
    for (int b = t; b < NBINS2; b += 1024)
        ftab_g[b] = make_float2(fv[b], fv[b + 1] - fv[b]);
    if (t == 0) {
        hdr[0] = d0;
        hdr[1] = rmx2;
        hdr[2] = (float)NBINS2 / fmaxf(rmx2 - d0, 1e-20f);
        hdr[3] = ssf[0];
    }

    // pull (sum of all target distances) + exact neighbor-pair subtraction
    float loc = 0.f, pul = 0.f;
    for (int idx = t; idx < 3 * N; idx += 1024) {
        float d = targetd[idx];
        pul += d;
        int lo = bsearch_gt(t2, d);
        if (lo < N) loc += ssf[lo] - d * (float)(N - lo);
    }
#pragma unroll
    for (int off = 32; off > 0; off >>= 1) {
        loc += __shfl_xor(loc, off, 64);
        pul += __shfl_xor(pul, off, 64);
    }
    __syncthreads();
    if (lane == 0) { aux[wid] = loc; aux[wid + 16] = pul; }
    __syncthreads();
    if (t == 0) {
        float s = 0.f, p = 0.f;
        for (int w = 0; w < 16; ++w) { s += aux[w]; p += aux[w + 16]; }
        accd[2] = (double)s;
        accd[0] = (double)p;
    }
}

// ---------------- fused bf16 MFMA Gram + chord-table push epilogue ----------------
template<int USEXB>
__global__ __launch_bounds__(256) void push_gemm_kernel(const float* __restrict__ X,
                                                        const __hip_bfloat16* __restrict__ Xb,
                                                        const float* __restrict__ x2,
                                                        const float2* __restrict__ ftab_g,
                                                        const float* __restrict__ hdr,
                                                        float* __restrict__ pp) {
    __shared__ __align__(16) char smem[32768];
    __shared__ float x2r[128], x2c[128];
    __shared__ float red[256];

    int bid = blockIdx.x;
    int by = 0, rem = bid;
    while (rem >= 32 - by) { rem -= 32 - by; ++by; }
    int bx = by + rem;
    int rowBase = by * 128, colBase = bx * 128;

    int tid = threadIdx.x;
    int lane = tid & 63;
    int wv = tid >> 6;
    int wy = wv >> 1, wx = wv & 1;

    floatx4 acc4[4][4];
#pragma unroll
    for (int m = 0; m < 4; ++m)
#pragma unroll
        for (int n = 0; n < 4; ++n) acc4[m][n] = (floatx4){0.f, 0.f, 0.f, 0.f};

    if (tid < 128) { x2r[tid] = x2[rowBase + tid]; x2c[tid] = x2[colBase + tid]; }

    for (int k0 = 0; k0 < DF; k0 += 64) {
        if (k0) __syncthreads();
        if (USEXB) {
            const __hip_bfloat16* Ab = Xb + (size_t)rowBase * DF;
            const __hip_bfloat16* Bb = Xb + (size_t)colBase * DF;
#pragma unroll
            for (int i = 0; i < 4; ++i) {
                int did = wv * 256 + i * 64 + lane;
                int row = ((did >> 7) << 4) | (did & 15);
                int kb = (did >> 4) & 7;
                size_t goff = (size_t)row * DF + k0 + kb * 8;
                char* ldsA = smem + (size_t)(wv * 256 + i * 64) * 16;
                gload_lds16(Ab + goff, ldsA);
                gload_lds16(Bb + goff, ldsA + 16384);
            }
        } else {
#pragma unroll
            for (int cch = 0; cch < 4; ++cch) {
                int did = tid + (cch << 8);
                int row = ((did >> 7) << 4) | (did & 15);
                int kb = (did >> 4) & 7;
                const float* srcA = X + (size_t)(rowBase + row) * DF + k0 + kb * 8;
                const float* srcB = X + (size_t)(colBase + row) * DF + k0 + kb * 8;
                float4 a0 = *(const float4*)srcA;
                float4 a1 = *(const float4*)(srcA + 4);
                float4 e0 = *(const float4*)srcB;
                float4 e1 = *(const float4*)(srcB + 4);
                ushort8v va, vb;
                va[0] = f2bf(a0.x); va[1] = f2bf(a0.y); va[2] = f2bf(a0.z); va[3] = f2bf(a0.w);
                va[4] = f2bf(a1.x); va[5] = f2bf(a1.y); va[6] = f2bf(a1.z); va[7] = f2bf(a1.w);
                vb[0] = f2bf(e0.x); vb[1] = f2bf(e0.y); vb[2] = f2bf(e0.z); vb[3] = f2bf(e0.w);
                vb[4] = f2bf(e1.x); vb[5] = f2bf(e1.y); vb[6] = f2bf(e1.z); vb[7] = f2bf(e1.w);
                *((ushort8v*)(smem + (did << 4))) = va;
                *((ushort8v*)(smem + 16384 + (did << 4))) = vb;
            }
        }
        __syncthreads();
#pragma unroll
        for (int kk = 0; kk < 2; ++kk) {
            short8v a[4], b[4];
#pragma unroll
            for (int m = 0; m < 4; ++m)
                a[m] = *((const short8v*)(smem + (((wy * 4 + m) * 2 + kk) << 10) + (lane << 4)));
#pragma unroll
            for (int n = 0; n < 4; ++n)
                b[n] = *((const short8v*)(smem + 16384 + (((wx * 4 + n) * 2 + kk) << 10) + (lane << 4)));
#pragma unroll
            for (int m = 0; m < 4; ++m)
#pragma unroll
                for (int n = 0; n < 4; ++n)
                    acc4[m][n] = __builtin_amdgcn_mfma_f32_16x16x32_bf16(a[m], b[n], acc4[m][n], 0, 0, 0);
        }
    }
    __syncthreads();

    float4* ft4 = (float4*)smem;
    for (int i = tid; i < 2048; i += 256) ft4[i] = ((const float4*)ftab_g)[i];
    __syncthreads();
    const float2* ftab = (const float2*)smem;
    float d0v = hdr[0], rmaxv = hdr[1], invw = hdr[2], Stot = hdr[3];
    bool diag = (by == bx);

    float local = 0.f;
    int g = lane >> 4;
    int cl = lane & 15;
#pragma unroll
    for (int m = 0; m < 4; ++m) {
#pragma unroll
        for (int n = 0; n < 4; ++n) {
            floatx4 v = acc4[m][n];
            int gcl = wx * 64 + n * 16 + cl;
            float x2cv = x2c[gcl];
#pragma unroll
            for (int r = 0; r < 4; ++r) {
                int grl = wy * 64 + m * 16 + g * 4 + r;
                if (diag && grl == gcl) continue;
                float d = fmaxf(x2r[grl] + x2cv - 2.f * v[r], 0.f);
                if (d >= rmaxv) continue;
                if (d < d0v) {
                    local += fmaf(-d, (float)N, Stot);
                } else {
                    float tpos = (d - d0v) * invw;
                    int b = min((int)tpos, NBINS2 - 1);
                    float frac = tpos - (float)b;
                    float2 ab = ftab[b];
                    local += fmaf(frac, ab.y, ab.x);
                }
            }
        }
    }
    red[tid] = local;
    __syncthreads();
    for (int s2 = 128; s2 > 0; s2 >>= 1) {
        if (tid < s2) red[tid] += red[tid + s2];
        __syncthreads();
    }
    if (tid == 0) {
        float wt = diag ? 1.f : 2.f;
        pp[bid] = wt * red[0];
    }
}

// ---------------- finalize: reduce 528 partials + combine ----------------
__global__ __launch_bounds__(256) void finalize_kernel(const double* __restrict__ accd,
                                                       const float* __restrict__ pp,
                                                       float* __restrict__ out) {
    __shared__ double wsum[4];
    int t = threadIdx.x;
    double s = 0.0;
    for (int i = t; i < NPUSHBLK; i += 256) s += (double)pp[i];
#pragma unroll
    for (int off = 32; off > 0; off >>= 1) s += __shfl_xor(s, off, 64);
    if ((t & 63) == 0) wsum[t >> 6] = s;
    __syncthreads();
    if (t == 0) {
        double tot = wsum[0] + wsum[1] + wsum[2] + wsum[3];
        out[0] = (float)((accd[0] + tot - accd[2]) / (double)N);
    }
}

extern "C" void kernel_launch(void* const* d_in, const int* in_sizes, int n_in,
                              void* d_out, int out_size, void* d_ws, size_t ws_size,
                              hipStream_t stream) {
    const float* X = (const float*)d_in[0];
    const int* labels = (const int*)d_in[1];
    float* out = (float*)d_out;

    char* w = (char*)d_ws;
    double* accd   = (double*)w;                        // 64 B
    float* x2      = (float*)(w + 64);                  // 16 KB
    float* radii   = (float*)(w + 64 + 16384);          // 16 KB
    float* targetd = (float*)(w + 64 + 32768);          // 48 KB
    int* cnt       = (int*)(w + 64 + 81920);            // 256 B
    int* members   = (int*)(w + 64 + 82176);            // 64 KB
    float* hdr     = (float*)(w + 64 + 147712);         // 64 B
    float2* ftab_g = (float2*)(w + 64 + 147776);        // 32 KB
    float* pp      = (float*)(w + 64 + 180544);         // 528 floats -> 4 KB
    __hip_bfloat16* Xb = (__hip_bfloat16*)(w + 64 + 184640); // 2 MB
    size_t need_xb = 64 + 184640 + (size_t)N * DF * 2;
    int useXb = (ws_size >= need_xb) ? 1 : 0;

    hipLaunchKernelGGL(prep_kernel, dim3(1025), dim3(256), 0, stream,
                       X, labels, x2, Xb, cnt, members, accd, useXb);
    hipLaunchKernelGGL(knn_class_kernel, dim3(16, 64), dim3(256), 0, stream,
                       X, x2, cnt, members, radii, targetd);
    hipLaunchKernelGGL(sort_scan_kernel, dim3(1), dim3(1024), 0, stream,
                       radii, targetd, ftab_g, hdr, accd);
    if (useXb)
        hipLaunchKernelGGL(push_gemm_kernel<1>, dim3(NPUSHBLK), dim3(256), 0, stream,
                           X, Xb, x2, ftab_g, hdr, pp);
    else
        hipLaunchKernelGGL(push_gemm_kernel<0>, dim3(NPUSHBLK), dim3(256), 0, stream,
                           X, Xb, x2, ftab_g, hdr, pp);
    hipLaunchKernelGGL(finalize_kernel, dim3(1), dim3(256), 0, stream, accd, pp, out);
}

// Round 7
// 98.250 us; speedup vs baseline: 1.5998x; 1.5648x over previous
//
#include <hip/hip_runtime.h>
#include <hip/hip_bf16.h>
#include <float.h>

#define N 4096
#define DF 256
#define NBINS2 4096
#define MAXM 128
#define NPUSHBLK 528

typedef __attribute__((ext_vector_type(8))) short short8v;
typedef __attribute__((ext_vector_type(8))) unsigned short ushort8v;
typedef __attribute__((ext_vector_type(4))) float floatx4;

__device__ inline unsigned short f2bf(float f) {
    __hip_bfloat16 h = __float2bfloat16(f);
    return *reinterpret_cast<unsigned short*>(&h);
}
__device__ inline float bf2f(unsigned short h) {
    unsigned int u = ((unsigned int)h) << 16;
    return __uint_as_float(u);
}

__device__ inline void gload_lds16(const void* g, void* l) {
    __builtin_amdgcn_global_load_lds((const __attribute__((address_space(1))) void*)g,
                                     (__attribute__((address_space(3))) void*)l, 16, 0, 0);
}

// ---------------- prep: x2 norms + bf16 convert + (extra block) class bucketing ----------------
__global__ __launch_bounds__(256) void prep_kernel(const float* __restrict__ X,
                                                   const int* __restrict__ labels,
                                                   float* __restrict__ x2,
                                                   __hip_bfloat16* __restrict__ Xb,
                                                   int* __restrict__ cnt,
                                                   int* __restrict__ members,
                                                   double* __restrict__ accd,
                                                   int useXb) {
    int t = threadIdx.x;
    if (blockIdx.x == 1024) {
        __shared__ int scnt[64];
        if (t < 8) accd[t] = 0.0;
        if (t < 64) scnt[t] = 0;
        __syncthreads();
        for (int i = t; i < N; i += 256) {
            int c = labels[i];
            int pos = atomicAdd(&scnt[c], 1);
            if (pos < MAXM) members[(c << 8) + pos] = i;
        }
        __syncthreads();
        if (t < 64) cnt[t] = min(scnt[t], MAXM);
        return;
    }
    int row = blockIdx.x * 4 + (t >> 6);
    int l = t & 63;
    int idx = row * 64 + l;
    float4 v = ((const float4*)X)[idx];
    if (useXb) {
        ushort4 o;
        o.x = f2bf(v.x); o.y = f2bf(v.y); o.z = f2bf(v.z); o.w = f2bf(v.w);
        ((ushort4*)Xb)[idx] = o;
    }
    float s = v.x * v.x + v.y * v.y + v.z * v.z + v.w * v.w;
#pragma unroll
    for (int off = 32; off > 0; off >>= 1) s += __shfl_xor(s, off, 64);
    if (l == 0) x2[row] = s;
}

// ---------------- per-class 3-NN via hi/lo bf16 MFMA Gram ----------------
__device__ inline void top3_upd(float& b0, float& b1, float& b2, float dd) {
    if (dd < b2) {
        if (dd < b1) { b2 = b1; if (dd < b0) { b1 = b0; b0 = dd; } else b1 = dd; }
        else b2 = dd;
    }
}

__global__ __launch_bounds__(512) void knn_mfma_kernel(const float* __restrict__ X,
                                                       const float* __restrict__ x2,
                                                       const int* __restrict__ cnt,
                                                       const int* __restrict__ members,
                                                       float* __restrict__ radii,
                                                       float* __restrict__ targetd) {
    // LDS: Hi [64 KB] + Lo [64 KB], frag-major: unit idx = rb*512 + kb*16 + r0  (16 B each)
    __shared__ __align__(16) char smem[131072];
    __shared__ int marr[MAXM];
    __shared__ float mx2[MAXM];

    int c = blockIdx.x;
    int m = cnt[c];
    int tid = threadIdx.x;
    int lane = tid & 63;
    int wid = tid >> 6;
    const int* mem = members + (c << 8);

    if (tid < MAXM) {
        int mi = (tid < m) ? mem[tid] : -1;
        marr[tid] = mi;
        mx2[tid] = (mi >= 0) ? x2[mi] : 0.f;
    }
    __syncthreads();

    int RB = (m + 15) >> 4;
    char* Hi = smem;
    char* Lo = smem + 65536;

    // stage hi/lo fragments
    for (int idx = tid; idx < RB * 512; idx += 512) {
        int rb = idx >> 9;
        int rem = idx & 511;
        int kb = rem >> 4;            // 0..31  (8 floats each)
        int r0 = rem & 15;
        int row = rb * 16 + r0;
        ushort8v vhi = (ushort8v){0,0,0,0,0,0,0,0};
        ushort8v vlo = vhi;
        if (row < m) {
            const float4* src = (const float4*)(X + (size_t)marr[row] * DF + kb * 8);
            float4 u0 = src[0], u1 = src[1];
            float uu[8] = {u0.x, u0.y, u0.z, u0.w, u1.x, u1.y, u1.z, u1.w};
#pragma unroll
            for (int p = 0; p < 8; ++p) {
                unsigned short h = f2bf(uu[p]);
                vhi[p] = h;
                vlo[p] = f2bf(uu[p] - bf2f(h));
            }
        }
        *((ushort8v*)(Hi + ((size_t)idx << 4))) = vhi;
        *((ushort8v*)(Lo + ((size_t)idx << 4))) = vlo;
    }
    __syncthreads();

    if (wid >= RB) return;

    // hoist A-fragments for this wave's 16-row stripe (stripe = wid)
    short8v aHi[8], aLo[8];
#pragma unroll
    for (int kk = 0; kk < 8; ++kk) {
        size_t off = (size_t)wid * 8192 + (size_t)kk * 1024 + ((size_t)lane << 4);
        aHi[kk] = *((const short8v*)(Hi + off));
        aLo[kk] = *((const short8v*)(Lo + off));
    }

    int g = lane >> 4;
    int cl = lane & 15;
    float x2i[4];
#pragma unroll
    for (int r = 0; r < 4; ++r) {
        int il = wid * 16 + g * 4 + r;
        x2i[r] = (il < MAXM) ? mx2[il] : 0.f;
    }

    float t0[4], t1[4], t2[4];
#pragma unroll
    for (int r = 0; r < 4; ++r) { t0[r] = FLT_MAX; t1[r] = FLT_MAX; t2[r] = FLT_MAX; }

    for (int ct = 0; ct < RB; ++ct) {
        floatx4 acc = (floatx4){0.f, 0.f, 0.f, 0.f};
#pragma unroll
        for (int kk = 0; kk < 8; ++kk) {
            size_t off = (size_t)ct * 8192 + (size_t)kk * 1024 + ((size_t)lane << 4);
            short8v bHi = *((const short8v*)(Hi + off));
            short8v bLo = *((const short8v*)(Lo + off));
            acc = __builtin_amdgcn_mfma_f32_16x16x32_bf16(aLo[kk], bHi, acc, 0, 0, 0);
            acc = __builtin_amdgcn_mfma_f32_16x16x32_bf16(aHi[kk], bLo, acc, 0, 0, 0);
            acc = __builtin_amdgcn_mfma_f32_16x16x32_bf16(aHi[kk], bHi, acc, 0, 0, 0);
        }
        int jl = ct * 16 + cl;
        float x2j = (jl < MAXM) ? mx2[jl] : 0.f;
#pragma unroll
        for (int r = 0; r < 4; ++r) {
            int il = wid * 16 + g * 4 + r;
            float d = fmaxf(x2i[r] + x2j - 2.f * acc[r], 0.f);
            bool valid = (jl < m) && (il < m) && (jl != il);
            top3_upd(t0[r], t1[r], t2[r], valid ? d : FLT_MAX);
        }
    }

    // merge top-3 across the 16 lanes sharing a row group (offs 1,2,4,8 stay in-group)
#pragma unroll
    for (int off = 1; off <= 8; off <<= 1) {
#pragma unroll
        for (int r = 0; r < 4; ++r) {
            float c0 = __shfl_xor(t0[r], off, 64);
            float c1 = __shfl_xor(t1[r], off, 64);
            float c2 = __shfl_xor(t2[r], off, 64);
            float m0, m1, m2;
            if (t0[r] <= c0) {
                m0 = t0[r];
                if (t1[r] <= c0) { m1 = t1[r]; m2 = fminf(t2[r], c0); }
                else { m1 = c0; m2 = fminf(t1[r], c1); }
            } else {
                m0 = c0;
                if (c1 <= t0[r]) { m1 = c1; m2 = fminf(c2, t0[r]); }
                else { m1 = t0[r]; m2 = fminf(c1, t1[r]); }
            }
            t0[r] = m0; t1[r] = m1; t2[r] = m2;
        }
    }
    if (cl == 0) {
#pragma unroll
        for (int r = 0; r < 4; ++r) {
            int il = wid * 16 + g * 4 + r;
            if (il < m) {
                int gi = marr[il];
                targetd[3 * gi + 0] = t0[r];
                targetd[3 * gi + 1] = t1[r];
                targetd[3 * gi + 2] = t2[r];
                radii[gi] = 1.f + t2[r];
            }
        }
    }
}

// ---------------- counting sort + chord table + pull + neighbor subtract ----------------
__device__ inline int bsearch_gt(const float* arr, float d) {
    int lo = 0, hi = N;
    while (lo < hi) {
        int mid = (lo + hi) >> 1;
        if (arr[mid] <= d) lo = mid + 1; else hi = mid;
    }
    return lo;
}

__global__ __launch_bounds__(1024) void sort_scan_kernel(const float* __restrict__ radii,
                                                         const float* __restrict__ targetd,
                                                         float2* __restrict__ ftab_g,
                                                         float* __restrict__ hdr,
                                                         double* __restrict__ accd) {
    __shared__ float t2[N];
    __shared__ int bcnt[N];
    __shared__ float fv[NBINS2 + 1];
    __shared__ float aux[64];
    __shared__ int iaux[16];
    int t = threadIdx.x;
    int wid = t >> 6, lane = t & 63;

    float4 vv = ((const float4*)radii)[t];
    float v0 = vv.x, v1 = vv.y, v2 = vv.z, v3 = vv.w;

    float mn = fminf(fminf(v0, v1), fminf(v2, v3));
    float mx = fmaxf(fmaxf(v0, v1), fmaxf(v2, v3));
#pragma unroll
    for (int off = 32; off > 0; off >>= 1) {
        mn = fminf(mn, __shfl_xor(mn, off, 64));
        mx = fmaxf(mx, __shfl_xor(mx, off, 64));
    }
    if (lane == 0) { aux[wid] = mn; aux[wid + 16] = mx; }
    bcnt[t] = 0; bcnt[t + 1024] = 0; bcnt[t + 2048] = 0; bcnt[t + 3072] = 0;
    __syncthreads();
    mn = aux[0]; mx = aux[16];
    for (int w = 1; w < 16; ++w) { mn = fminf(mn, aux[w]); mx = fmaxf(mx, aux[w + 16]); }
    float range = fmaxf(mx - mn, 1e-30f);
    float scale = (float)N / range * (1.f - 1e-6f);

    int b0i = max(0, min((int)((v0 - mn) * scale), N - 1));
    int b1i = max(0, min((int)((v1 - mn) * scale), N - 1));
    int b2i = max(0, min((int)((v2 - mn) * scale), N - 1));
    int b3i = max(0, min((int)((v3 - mn) * scale), N - 1));
    atomicAdd(&bcnt[b0i], 1); atomicAdd(&bcnt[b1i], 1);
    atomicAdd(&bcnt[b2i], 1); atomicAdd(&bcnt[b3i], 1);
    __syncthreads();

    int c0i = bcnt[4 * t], c1i = bcnt[4 * t + 1], c2i = bcnt[4 * t + 2], c3i = bcnt[4 * t + 3];
    int tot_i = c0i + c1i + c2i + c3i;
    int sc = tot_i;
#pragma unroll
    for (int off = 1; off < 64; off <<= 1) {
        int y = __shfl_up(sc, off, 64);
        if (lane >= off) sc += y;
    }
    if (lane == 63) iaux[wid] = sc;
    __syncthreads();
    if (t < 16) {
        int wv2 = iaux[t];
        int s = wv2;
#pragma unroll
        for (int off = 1; off < 16; off <<= 1) {
            int y = __shfl_up(s, off, 64);
            if (t >= off) s += y;
        }
        iaux[t] = s - wv2;
    }
    __syncthreads();
    int base = iaux[wid] + (sc - tot_i);
    int e0 = base, e1 = base + c0i, e2 = e1 + c1i, e3 = e2 + c2i;
    bcnt[4 * t] = e0; bcnt[4 * t + 1] = e1; bcnt[4 * t + 2] = e2; bcnt[4 * t + 3] = e3;
    __syncthreads();

    t2[atomicAdd(&bcnt[b0i], 1)] = v0;
    t2[atomicAdd(&bcnt[b1i], 1)] = v1;
    t2[atomicAdd(&bcnt[b2i], 1)] = v2;
    t2[atomicAdd(&bcnt[b3i], 1)] = v3;
    __syncthreads();

#pragma unroll
    for (int r = 0; r < 4; ++r) {
        int b = 4 * t + r;
        int st = b ? bcnt[b - 1] : 0;
        int en = bcnt[b];
        for (int a = st + 1; a < en; ++a) {
            float key = t2[a];
            int q = a - 1;
            while (q >= st && t2[q] > key) { t2[q + 1] = t2[q]; --q; }
            t2[q + 1] = key;
        }
    }
    __syncthreads();

    float w0 = t2[4 * t], w1 = t2[4 * t + 1], w2 = t2[4 * t + 2], w3 = t2[4 * t + 3];
    float tot4 = w0 + w1 + w2 + w3;
    float sfx = tot4;
#pragma unroll
    for (int off = 1; off < 64; off <<= 1) {
        float y = __shfl_down(sfx, off, 64);
        if (lane + off < 64) sfx += y;
    }
    if (lane == 0) aux[wid] = sfx;
    __syncthreads();
    if (t < 16) {
        float x = aux[t];
        float s = x;
#pragma unroll
        for (int off = 1; off < 16; off <<= 1) {
            float y = __shfl_down(s, off, 64);
            if (t + off < 16) s += y;
        }
        aux[t] = s - x;
    }
    __syncthreads();
    float after = aux[wid] + (sfx - tot4);
    float q3 = w3 + after, q2 = w2 + q3, q1 = w1 + q2, q0 = w0 + q1;
    float* ssf = (float*)bcnt;
    ssf[4 * t] = q0; ssf[4 * t + 1] = q1; ssf[4 * t + 2] = q2; ssf[4 * t + 3] = q3;
    __syncthreads();

    float d0 = t2[0], rmx2 = t2[N - 1];
    float wbin = fmaxf(rmx2 - d0, 1e-20f) / (float)NBINS2;
    for (int e = t; e <= NBINS2; e += 1024) {
        float x = d0 + wbin * (float)e;
        int lo = bsearch_gt(t2, x);
        float Sv = (lo < N) ? ssf[lo] : 0.f;
        fv[e] = Sv - x * (float)(N - lo);
    }
    __syncthreads();
    for (int b = t; b < NBINS2; b += 1024)
        ftab_g[b] = make_float2(fv[b], fv[b + 1] - fv[b]);
    if (t == 0) {
        hdr[0] = d0;
        hdr[1] = rmx2;
        hdr[2] = (float)NBINS2 / fmaxf(rmx2 - d0, 1e-20f);
        hdr[3] = ssf[0];
    }

    // pull (sum of target distances) + exact neighbor-pair subtraction
    float loc = 0.f, pul = 0.f;
    for (int idx = t; idx < 3 * N; idx += 1024) {
        float d = targetd[idx];
        pul += d;
        int lo = bsearch_gt(t2, d);
        if (lo < N) loc += ssf[lo] - d * (float)(N - lo);
    }
#pragma unroll
    for (int off = 32; off > 0; off >>= 1) {
        loc += __shfl_xor(loc, off, 64);
        pul += __shfl_xor(pul, off, 64);
    }
    __syncthreads();
    if (lane == 0) { aux[wid] = loc; aux[wid + 16] = pul; }
    __syncthreads();
    if (t == 0) {
        float s = 0.f, p = 0.f;
        for (int w = 0; w < 16; ++w) { s += aux[w]; p += aux[w + 16]; }
        accd[2] = (double)s;
        accd[0] = (double)p;
    }
}

// ---------------- fused bf16 MFMA Gram + chord-table push epilogue ----------------
template<int USEXB>
__global__ __launch_bounds__(256) void push_gemm_kernel(const float* __restrict__ X,
                                                        const __hip_bfloat16* __restrict__ Xb,
                                                        const float* __restrict__ x2,
                                                        const float2* __restrict__ ftab_g,
                                                        const float* __restrict__ hdr,
                                                        float* __restrict__ pp) {
    __shared__ __align__(16) char smem[32768];
    __shared__ float x2r[128], x2c[128];
    __shared__ float red[256];

    int bid = blockIdx.x;
    int by = 0, rem = bid;
    while (rem >= 32 - by) { rem -= 32 - by; ++by; }
    int bx = by + rem;
    int rowBase = by * 128, colBase = bx * 128;

    int tid = threadIdx.x;
    int lane = tid & 63;
    int wv = tid >> 6;
    int wy = wv >> 1, wx = wv & 1;

    floatx4 acc4[4][4];
#pragma unroll
    for (int m = 0; m < 4; ++m)
#pragma unroll
        for (int n = 0; n < 4; ++n) acc4[m][n] = (floatx4){0.f, 0.f, 0.f, 0.f};

    if (tid < 128) { x2r[tid] = x2[rowBase + tid]; x2c[tid] = x2[colBase + tid]; }

    for (int k0 = 0; k0 < DF; k0 += 64) {
        if (k0) __syncthreads();
        if (USEXB) {
            const __hip_bfloat16* Ab = Xb + (size_t)rowBase * DF;
            const __hip_bfloat16* Bb = Xb + (size_t)colBase * DF;
#pragma unroll
            for (int i = 0; i < 4; ++i) {
                int did = wv * 256 + i * 64 + lane;
                int row = ((did >> 7) << 4) | (did & 15);
                int kb = (did >> 4) & 7;
                size_t goff = (size_t)row * DF + k0 + kb * 8;
                char* ldsA = smem + (size_t)(wv * 256 + i * 64) * 16;
                gload_lds16(Ab + goff, ldsA);
                gload_lds16(Bb + goff, ldsA + 16384);
            }
        } else {
#pragma unroll
            for (int cch = 0; cch < 4; ++cch) {
                int did = tid + (cch << 8);
                int row = ((did >> 7) << 4) | (did & 15);
                int kb = (did >> 4) & 7;
                const float* srcA = X + (size_t)(rowBase + row) * DF + k0 + kb * 8;
                const float* srcB = X + (size_t)(colBase + row) * DF + k0 + kb * 8;
                float4 a0 = *(const float4*)srcA;
                float4 a1 = *(const float4*)(srcA + 4);
                float4 e0 = *(const float4*)srcB;
                float4 e1 = *(const float4*)(srcB + 4);
                ushort8v va, vb;
                va[0] = f2bf(a0.x); va[1] = f2bf(a0.y); va[2] = f2bf(a0.z); va[3] = f2bf(a0.w);
                va[4] = f2bf(a1.x); va[5] = f2bf(a1.y); va[6] = f2bf(a1.z); va[7] = f2bf(a1.w);
                vb[0] = f2bf(e0.x); vb[1] = f2bf(e0.y); vb[2] = f2bf(e0.z); vb[3] = f2bf(e0.w);
                vb[4] = f2bf(e1.x); vb[5] = f2bf(e1.y); vb[6] = f2bf(e1.z); vb[7] = f2bf(e1.w);
                *((ushort8v*)(smem + (did << 4))) = va;
                *((ushort8v*)(smem + 16384 + (did << 4))) = vb;
            }
        }
        __syncthreads();
#pragma unroll
        for (int kk = 0; kk < 2; ++kk) {
            short8v a[4], b[4];
#pragma unroll
            for (int m = 0; m < 4; ++m)
                a[m] = *((const short8v*)(smem + (((wy * 4 + m) * 2 + kk) << 10) + (lane << 4)));
#pragma unroll
            for (int n = 0; n < 4; ++n)
                b[n] = *((const short8v*)(smem + 16384 + (((wx * 4 + n) * 2 + kk) << 10) + (lane << 4)));
#pragma unroll
            for (int m = 0; m < 4; ++m)
#pragma unroll
                for (int n = 0; n < 4; ++n)
                    acc4[m][n] = __builtin_amdgcn_mfma_f32_16x16x32_bf16(a[m], b[n], acc4[m][n], 0, 0, 0);
        }
    }
    __syncthreads();

    float4* ft4 = (float4*)smem;
    for (int i = tid; i < 2048; i += 256) ft4[i] = ((const float4*)ftab_g)[i];
    __syncthreads();
    const float2* ftab = (const float2*)smem;
    float d0v = hdr[0], rmaxv = hdr[1], invw = hdr[2], Stot = hdr[3];
    bool diag = (by == bx);

    float local = 0.f;
    int g = lane >> 4;
    int cl = lane & 15;
#pragma unroll
    for (int m = 0; m < 4; ++m) {
#pragma unroll
        for (int n = 0; n < 4; ++n) {
            floatx4 v = acc4[m][n];
            int gcl = wx * 64 + n * 16 + cl;
            float x2cv = x2c[gcl];
#pragma unroll
            for (int r = 0; r < 4; ++r) {
                int grl = wy * 64 + m * 16 + g * 4 + r;
                if (diag && grl == gcl) continue;
                float d = fmaxf(x2r[grl] + x2cv - 2.f * v[r], 0.f);
                if (d >= rmaxv) continue;
                if (d < d0v) {
                    local += fmaf(-d, (float)N, Stot);
                } else {
                    float tpos = (d - d0v) * invw;
                    int b = min((int)tpos, NBINS2 - 1);
                    float frac = tpos - (float)b;
                    float2 ab = ftab[b];
                    local += fmaf(frac, ab.y, ab.x);
                }
            }
        }
    }
    red[tid] = local;
    __syncthreads();
    for (int s2 = 128; s2 > 0; s2 >>= 1) {
        if (tid < s2) red[tid] += red[tid + s2];
        __syncthreads();
    }
    if (tid == 0) {
        float wt = diag ? 1.f : 2.f;
        pp[bid] = wt * red[0];
    }
}

// ---------------- finalize: reduce 528 partials + combine ----------------
__global__ __launch_bounds__(256) void finalize_kernel(const double* __restrict__ accd,
                                                       const float* __restrict__ pp,
                                                       float* __restrict__ out) {
    __shared__ double wsum[4];
    int t = threadIdx.x;
    double s = 0.0;
    for (int i = t; i < NPUSHBLK; i += 256) s += (double)pp[i];
#pragma unroll
    for (int off = 32; off > 0; off >>= 1) s += __shfl_xor(s, off, 64);
    if ((t & 63) == 0) wsum[t >> 6] = s;
    __syncthreads();
    if (t == 0) {
        double tot = wsum[0] + wsum[1] + wsum[2] + wsum[3];
        out[0] = (float)((accd[0] + tot - accd[2]) / (double)N);
    }
}

extern "C" void kernel_launch(void* const* d_in, const int* in_sizes, int n_in,
                              void* d_out, int out_size, void* d_ws, size_t ws_size,
                              hipStream_t stream) {
    const float* X = (const float*)d_in[0];
    const int* labels = (const int*)d_in[1];
    float* out = (float*)d_out;

    char* w = (char*)d_ws;
    double* accd   = (double*)w;                        // 64 B
    float* x2      = (float*)(w + 64);                  // 16 KB
    float* radii   = (float*)(w + 64 + 16384);          // 16 KB
    float* targetd = (float*)(w + 64 + 32768);          // 48 KB
    int* cnt       = (int*)(w + 64 + 81920);            // 256 B
    int* members   = (int*)(w + 64 + 82176);            // 64 KB
    float* hdr     = (float*)(w + 64 + 147712);         // 64 B
    float2* ftab_g = (float2*)(w + 64 + 147776);        // 32 KB
    float* pp      = (float*)(w + 64 + 180544);         // 528 floats -> 4 KB
    __hip_bfloat16* Xb = (__hip_bfloat16*)(w + 64 + 184640); // 2 MB
    size_t need_xb = 64 + 184640 + (size_t)N * DF * 2;
    int useXb = (ws_size >= need_xb) ? 1 : 0;

    hipLaunchKernelGGL(prep_kernel, dim3(1025), dim3(256), 0, stream,
                       X, labels, x2, Xb, cnt, members, accd, useXb);
    hipLaunchKernelGGL(knn_mfma_kernel, dim3(64), dim3(512), 0, stream,
                       X, x2, cnt, members, radii, targetd);
    hipLaunchKernelGGL(sort_scan_kernel, dim3(1), dim3(1024), 0, stream,
                       radii, targetd, ftab_g, hdr, accd);
    if (useXb)
        hipLaunchKernelGGL(push_gemm_kernel<1>, dim3(NPUSHBLK), dim3(256), 0, stream,
                           X, Xb, x2, ftab_g, hdr, pp);
    else
        hipLaunchKernelGGL(push_gemm_kernel<0>, dim3(NPUSHBLK), dim3(256), 0, stream,
                           X, Xb, x2, ftab_g, hdr, pp);
    hipLaunchKernelGGL(finalize_kernel, dim3(1), dim3(256), 0, stream, accd, pp, out);
}

// Round 8
// 68.918 us; speedup vs baseline: 2.2807x; 1.4256x over previous
//
#include <hip/hip_runtime.h>
#include <hip/hip_bf16.h>
#include <float.h>

#define N 4096
#define DF 256
#define NBINS2 4096
#define MAXM 128
#define NPUSHBLK 528

typedef __attribute__((ext_vector_type(8))) short short8v;
typedef __attribute__((ext_vector_type(8))) unsigned short ushort8v;
typedef __attribute__((ext_vector_type(4))) float floatx4;

__device__ inline unsigned short f2bf(float f) {
    __hip_bfloat16 h = __float2bfloat16(f);
    return *reinterpret_cast<unsigned short*>(&h);
}
__device__ inline float bf2f(unsigned short h) {
    unsigned int u = ((unsigned int)h) << 16;
    return __uint_as_float(u);
}

__device__ inline void gload_lds16(const void* g, void* l) {
    __builtin_amdgcn_global_load_lds((const __attribute__((address_space(1))) void*)g,
                                     (__attribute__((address_space(3))) void*)l, 16, 0, 0);
}

// ---------------- prep: x2 norms + bf16 convert + (extra block) class bucketing ----------------
__global__ __launch_bounds__(256) void prep_kernel(const float* __restrict__ X,
                                                   const int* __restrict__ labels,
                                                   float* __restrict__ x2,
                                                   __hip_bfloat16* __restrict__ Xb,
                                                   int* __restrict__ cnt,
                                                   int* __restrict__ members,
                                                   double* __restrict__ accd,
                                                   int useXb) {
    int t = threadIdx.x;
    if (blockIdx.x == 1024) {
        __shared__ int scnt[64];
        if (t < 8) accd[t] = 0.0;
        if (t < 64) scnt[t] = 0;
        __syncthreads();
        for (int i = t; i < N; i += 256) {
            int c = labels[i];
            int pos = atomicAdd(&scnt[c], 1);
            if (pos < MAXM) members[(c << 8) + pos] = i;
        }
        __syncthreads();
        if (t < 64) cnt[t] = min(scnt[t], MAXM);
        return;
    }
    int row = blockIdx.x * 4 + (t >> 6);
    int l = t & 63;
    int idx = row * 64 + l;
    float4 v = ((const float4*)X)[idx];
    if (useXb) {
        ushort4 o;
        o.x = f2bf(v.x); o.y = f2bf(v.y); o.z = f2bf(v.z); o.w = f2bf(v.w);
        ((ushort4*)Xb)[idx] = o;
    }
    float s = v.x * v.x + v.y * v.y + v.z * v.z + v.w * v.w;
#pragma unroll
    for (int off = 32; off > 0; off >>= 1) s += __shfl_xor(s, off, 64);
    if (l == 0) x2[row] = s;
}

// ---------------- per-class 3-NN via hi/lo bf16 MFMA Gram ----------------
__device__ inline void top3_upd(float& b0, float& b1, float& b2, float dd) {
    if (dd < b2) {
        if (dd < b1) { b2 = b1; if (dd < b0) { b1 = b0; b0 = dd; } else b1 = dd; }
        else b2 = dd;
    }
}

__global__ __launch_bounds__(512) void knn_mfma_kernel(const float* __restrict__ X,
                                                       const float* __restrict__ x2,
                                                       const int* __restrict__ cnt,
                                                       const int* __restrict__ members,
                                                       float* __restrict__ radii,
                                                       float* __restrict__ targetd) {
    __shared__ __align__(16) char smem[131072];
    __shared__ int marr[MAXM];
    __shared__ float mx2[MAXM];

    int c = blockIdx.x;
    int m = cnt[c];
    int tid = threadIdx.x;
    int lane = tid & 63;
    int wid = tid >> 6;
    const int* mem = members + (c << 8);

    if (tid < MAXM) {
        int mi = (tid < m) ? mem[tid] : -1;
        marr[tid] = mi;
        mx2[tid] = (mi >= 0) ? x2[mi] : 0.f;
    }
    __syncthreads();

    int RB = (m + 15) >> 4;
    char* Hi = smem;
    char* Lo = smem + 65536;

    for (int idx = tid; idx < RB * 512; idx += 512) {
        int rb = idx >> 9;
        int rem = idx & 511;
        int kb = rem >> 4;
        int r0 = rem & 15;
        int row = rb * 16 + r0;
        ushort8v vhi = (ushort8v){0,0,0,0,0,0,0,0};
        ushort8v vlo = vhi;
        if (row < m) {
            const float4* src = (const float4*)(X + (size_t)marr[row] * DF + kb * 8);
            float4 u0 = src[0], u1 = src[1];
            float uu[8] = {u0.x, u0.y, u0.z, u0.w, u1.x, u1.y, u1.z, u1.w};
#pragma unroll
            for (int p = 0; p < 8; ++p) {
                unsigned short h = f2bf(uu[p]);
                vhi[p] = h;
                vlo[p] = f2bf(uu[p] - bf2f(h));
            }
        }
        *((ushort8v*)(Hi + ((size_t)idx << 4))) = vhi;
        *((ushort8v*)(Lo + ((size_t)idx << 4))) = vlo;
    }
    __syncthreads();

    if (wid >= RB) return;

    short8v aHi[8], aLo[8];
#pragma unroll
    for (int kk = 0; kk < 8; ++kk) {
        size_t off = (size_t)wid * 8192 + (size_t)kk * 1024 + ((size_t)lane << 4);
        aHi[kk] = *((const short8v*)(Hi + off));
        aLo[kk] = *((const short8v*)(Lo + off));
    }

    int g = lane >> 4;
    int cl = lane & 15;
    float x2i[4];
#pragma unroll
    for (int r = 0; r < 4; ++r) {
        int il = wid * 16 + g * 4 + r;
        x2i[r] = (il < MAXM) ? mx2[il] : 0.f;
    }

    float t0[4], t1[4], t2[4];
#pragma unroll
    for (int r = 0; r < 4; ++r) { t0[r] = FLT_MAX; t1[r] = FLT_MAX; t2[r] = FLT_MAX; }

    for (int ct = 0; ct < RB; ++ct) {
        floatx4 acc = (floatx4){0.f, 0.f, 0.f, 0.f};
#pragma unroll
        for (int kk = 0; kk < 8; ++kk) {
            size_t off = (size_t)ct * 8192 + (size_t)kk * 1024 + ((size_t)lane << 4);
            short8v bHi = *((const short8v*)(Hi + off));
            short8v bLo = *((const short8v*)(Lo + off));
            acc = __builtin_amdgcn_mfma_f32_16x16x32_bf16(aLo[kk], bHi, acc, 0, 0, 0);
            acc = __builtin_amdgcn_mfma_f32_16x16x32_bf16(aHi[kk], bLo, acc, 0, 0, 0);
            acc = __builtin_amdgcn_mfma_f32_16x16x32_bf16(aHi[kk], bHi, acc, 0, 0, 0);
        }
        int jl = ct * 16 + cl;
        float x2j = (jl < MAXM) ? mx2[jl] : 0.f;
#pragma unroll
        for (int r = 0; r < 4; ++r) {
            int il = wid * 16 + g * 4 + r;
            float d = fmaxf(x2i[r] + x2j - 2.f * acc[r], 0.f);
            bool valid = (jl < m) && (il < m) && (jl != il);
            top3_upd(t0[r], t1[r], t2[r], valid ? d : FLT_MAX);
        }
    }

#pragma unroll
    for (int off = 1; off <= 8; off <<= 1) {
#pragma unroll
        for (int r = 0; r < 4; ++r) {
            float c0 = __shfl_xor(t0[r], off, 64);
            float c1 = __shfl_xor(t1[r], off, 64);
            float c2 = __shfl_xor(t2[r], off, 64);
            float m0, m1, m2;
            if (t0[r] <= c0) {
                m0 = t0[r];
                if (t1[r] <= c0) { m1 = t1[r]; m2 = fminf(t2[r], c0); }
                else { m1 = c0; m2 = fminf(t1[r], c1); }
            } else {
                m0 = c0;
                if (c1 <= t0[r]) { m1 = c1; m2 = fminf(c2, t0[r]); }
                else { m1 = t0[r]; m2 = fminf(c1, t1[r]); }
            }
            t0[r] = m0; t1[r] = m1; t2[r] = m2;
        }
    }
    if (cl == 0) {
#pragma unroll
        for (int r = 0; r < 4; ++r) {
            int il = wid * 16 + g * 4 + r;
            if (il < m) {
                int gi = marr[il];
                targetd[3 * gi + 0] = t0[r];
                targetd[3 * gi + 1] = t1[r];
                targetd[3 * gi + 2] = t2[r];
                radii[gi] = 1.f + t2[r];
            }
        }
    }
}

// ---------------- histogram + suffix scan -> chord table; pull + neighbor subtract ----------------
__global__ __launch_bounds__(1024) void histo_ftab_kernel(const float* __restrict__ radii,
                                                          const float* __restrict__ targetd,
                                                          float2* __restrict__ ftab_g,
                                                          float* __restrict__ hdr,
                                                          double* __restrict__ accd) {
    __shared__ int cntb[NBINS2];
    __shared__ float sumb[NBINS2];
    __shared__ float fv[NBINS2 + 1];
    __shared__ float aux[64];
    __shared__ int iaux[16];
    int t = threadIdx.x;
    int wid = t >> 6, lane = t & 63;

    float4 vv = ((const float4*)radii)[t];
    float v0 = vv.x, v1 = vv.y, v2 = vv.z, v3 = vv.w;

    // min/max reduce
    float mn = fminf(fminf(v0, v1), fminf(v2, v3));
    float mx = fmaxf(fmaxf(v0, v1), fmaxf(v2, v3));
#pragma unroll
    for (int off = 32; off > 0; off >>= 1) {
        mn = fminf(mn, __shfl_xor(mn, off, 64));
        mx = fmaxf(mx, __shfl_xor(mx, off, 64));
    }
    if (lane == 0) { aux[wid] = mn; aux[wid + 16] = mx; }
    cntb[t] = 0; cntb[t + 1024] = 0; cntb[t + 2048] = 0; cntb[t + 3072] = 0;
    sumb[t] = 0.f; sumb[t + 1024] = 0.f; sumb[t + 2048] = 0.f; sumb[t + 3072] = 0.f;
    __syncthreads();
    mn = aux[0]; mx = aux[16];
    for (int w = 1; w < 16; ++w) { mn = fminf(mn, aux[w]); mx = fmaxf(mx, aux[w + 16]); }
    float range = fmaxf(mx - mn, 1e-30f);
    float scale = (float)NBINS2 / range * (1.f - 1e-6f);

    // histogram: per-bin count + sum
    int b0i = max(0, min((int)((v0 - mn) * scale), NBINS2 - 1));
    int b1i = max(0, min((int)((v1 - mn) * scale), NBINS2 - 1));
    int b2i = max(0, min((int)((v2 - mn) * scale), NBINS2 - 1));
    int b3i = max(0, min((int)((v3 - mn) * scale), NBINS2 - 1));
    atomicAdd(&cntb[b0i], 1); atomicAdd(&sumb[b0i], v0);
    atomicAdd(&cntb[b1i], 1); atomicAdd(&sumb[b1i], v1);
    atomicAdd(&cntb[b2i], 1); atomicAdd(&sumb[b2i], v2);
    atomicAdd(&cntb[b3i], 1); atomicAdd(&sumb[b3i], v3);
    __syncthreads();

    // suffix scan (inclusive, from high bins down) of (cnt, sum)
    int c0 = cntb[4 * t], c1 = cntb[4 * t + 1], c2 = cntb[4 * t + 2], c3 = cntb[4 * t + 3];
    float s0 = sumb[4 * t], s1 = sumb[4 * t + 1], s2 = sumb[4 * t + 2], s3 = sumb[4 * t + 3];
    int toti = c0 + c1 + c2 + c3;
    float totf = s0 + s1 + s2 + s3;
    int sci = toti;
    float scf = totf;
#pragma unroll
    for (int off = 1; off < 64; off <<= 1) {
        int yi = __shfl_down(sci, off, 64);
        float yf = __shfl_down(scf, off, 64);
        if (lane + off < 64) { sci += yi; scf += yf; }
    }
    if (lane == 0) { iaux[wid] = sci; aux[wid] = scf; }
    __syncthreads();
    if (t < 16) {
        int xi = iaux[t];
        float xf = aux[t];
        int si = xi;
        float sf = xf;
#pragma unroll
        for (int off = 1; off < 16; off <<= 1) {
            int yi = __shfl_down(si, off, 64);
            float yf = __shfl_down(sf, off, 64);
            if (t + off < 16) { si += yi; sf += yf; }
        }
        iaux[t] = si - xi;     // strictly-after wave sums
        aux[t] = sf - xf;
    }
    __syncthreads();
    int afteri = iaux[wid] + (sci - toti);
    float afterf = aux[wid] + (scf - totf);
    int C3 = c3 + afteri, C2 = c2 + C3, C1 = c1 + C2, C0 = c0 + C1;
    float S3 = s3 + afterf, S2 = s2 + S3, S1 = s1 + S2, S0 = s0 + S1;

    // exact-at-edges f values: f_e = S_e - x_e * C_e  (suffix aggregates from bin e)
    float wbin = range / (float)NBINS2;
    {
        float x0 = mn + wbin * (float)(4 * t);
        fv[4 * t + 0] = S0 - x0 * (float)C0;
        float x1 = mn + wbin * (float)(4 * t + 1);
        fv[4 * t + 1] = S1 - x1 * (float)C1;
        float x2e = mn + wbin * (float)(4 * t + 2);
        fv[4 * t + 2] = S2 - x2e * (float)C2;
        float x3 = mn + wbin * (float)(4 * t + 3);
        fv[4 * t + 3] = S3 - x3 * (float)C3;
    }
    if (t == 0) fv[NBINS2] = 0.f;
    __syncthreads();

    for (int b = t; b < NBINS2; b += 1024)
        ftab_g[b] = make_float2(fv[b], fv[b + 1] - fv[b]);
    float Stot = fv[0] + mn * (float)N;   // = sum of all radii
    if (t == 0) {
        hdr[0] = mn;
        hdr[1] = mx;
        hdr[2] = (float)NBINS2 / fmaxf(mx - mn, 1e-20f);
        hdr[3] = Stot;
    }

    // pull + chord-based neighbor-pair subtraction
    float invw = (float)NBINS2 / fmaxf(mx - mn, 1e-20f);
    float loc = 0.f, pul = 0.f;
    for (int idx = t; idx < 3 * N; idx += 1024) {
        float d = targetd[idx];
        pul += d;
        if (d >= mx) continue;
        if (d < mn) {
            loc += fmaf(-d, (float)N, Stot);
        } else {
            float tpos = (d - mn) * invw;
            int b = min((int)tpos, NBINS2 - 1);
            float frac = tpos - (float)b;
            loc += fmaf(frac, fv[b + 1] - fv[b], fv[b]);
        }
    }
#pragma unroll
    for (int off = 32; off > 0; off >>= 1) {
        loc += __shfl_xor(loc, off, 64);
        pul += __shfl_xor(pul, off, 64);
    }
    __syncthreads();
    if (lane == 0) { aux[wid] = loc; aux[wid + 16] = pul; }
    __syncthreads();
    if (t == 0) {
        float s = 0.f, p = 0.f;
        for (int w = 0; w < 16; ++w) { s += aux[w]; p += aux[w + 16]; }
        accd[2] = (double)s;
        accd[0] = (double)p;
    }
}

// ---------------- fused bf16 MFMA Gram + chord-table push epilogue ----------------
template<int USEXB>
__global__ __launch_bounds__(256) void push_gemm_kernel(const float* __restrict__ X,
                                                        const __hip_bfloat16* __restrict__ Xb,
                                                        const float* __restrict__ x2,
                                                        const float2* __restrict__ ftab_g,
                                                        const float* __restrict__ hdr,
                                                        float* __restrict__ pp) {
    __shared__ __align__(16) char smem[32768];
    __shared__ float x2r[128], x2c[128];
    __shared__ float red[256];

    int bid = blockIdx.x;
    int by = 0, rem = bid;
    while (rem >= 32 - by) { rem -= 32 - by; ++by; }
    int bx = by + rem;
    int rowBase = by * 128, colBase = bx * 128;

    int tid = threadIdx.x;
    int lane = tid & 63;
    int wv = tid >> 6;
    int wy = wv >> 1, wx = wv & 1;

    floatx4 acc4[4][4];
#pragma unroll
    for (int m = 0; m < 4; ++m)
#pragma unroll
        for (int n = 0; n < 4; ++n) acc4[m][n] = (floatx4){0.f, 0.f, 0.f, 0.f};

    if (tid < 128) { x2r[tid] = x2[rowBase + tid]; x2c[tid] = x2[colBase + tid]; }

    for (int k0 = 0; k0 < DF; k0 += 64) {
        if (k0) __syncthreads();
        if (USEXB) {
            const __hip_bfloat16* Ab = Xb + (size_t)rowBase * DF;
            const __hip_bfloat16* Bb = Xb + (size_t)colBase * DF;
#pragma unroll
            for (int i = 0; i < 4; ++i) {
                int did = wv * 256 + i * 64 + lane;
                int row = ((did >> 7) << 4) | (did & 15);
                int kb = (did >> 4) & 7;
                size_t goff = (size_t)row * DF + k0 + kb * 8;
                char* ldsA = smem + (size_t)(wv * 256 + i * 64) * 16;
                gload_lds16(Ab + goff, ldsA);
                gload_lds16(Bb + goff, ldsA + 16384);
            }
        } else {
#pragma unroll
            for (int cch = 0; cch < 4; ++cch) {
                int did = tid + (cch << 8);
                int row = ((did >> 7) << 4) | (did & 15);
                int kb = (did >> 4) & 7;
                const float* srcA = X + (size_t)(rowBase + row) * DF + k0 + kb * 8;
                const float* srcB = X + (size_t)(colBase + row) * DF + k0 + kb * 8;
                float4 a0 = *(const float4*)srcA;
                float4 a1 = *(const float4*)(srcA + 4);
                float4 e0 = *(const float4*)srcB;
                float4 e1 = *(const float4*)(srcB + 4);
                ushort8v va, vb;
                va[0] = f2bf(a0.x); va[1] = f2bf(a0.y); va[2] = f2bf(a0.z); va[3] = f2bf(a0.w);
                va[4] = f2bf(a1.x); va[5] = f2bf(a1.y); va[6] = f2bf(a1.z); va[7] = f2bf(a1.w);
                vb[0] = f2bf(e0.x); vb[1] = f2bf(e0.y); vb[2] = f2bf(e0.z); vb[3] = f2bf(e0.w);
                vb[4] = f2bf(e1.x); vb[5] = f2bf(e1.y); vb[6] = f2bf(e1.z); vb[7] = f2bf(e1.w);
                *((ushort8v*)(smem + (did << 4))) = va;
                *((ushort8v*)(smem + 16384 + (did << 4))) = vb;
            }
        }
        __syncthreads();
#pragma unroll
        for (int kk = 0; kk < 2; ++kk) {
            short8v a[4], b[4];
#pragma unroll
            for (int m = 0; m < 4; ++m)
                a[m] = *((const short8v*)(smem + (((wy * 4 + m) * 2 + kk) << 10) + (lane << 4)));
#pragma unroll
            for (int n = 0; n < 4; ++n)
                b[n] = *((const short8v*)(smem + 16384 + (((wx * 4 + n) * 2 + kk) << 10) + (lane << 4)));
#pragma unroll
            for (int m = 0; m < 4; ++m)
#pragma unroll
                for (int n = 0; n < 4; ++n)
                    acc4[m][n] = __builtin_amdgcn_mfma_f32_16x16x32_bf16(a[m], b[n], acc4[m][n], 0, 0, 0);
        }
    }
    __syncthreads();

    float4* ft4 = (float4*)smem;
    for (int i = tid; i < 2048; i += 256) ft4[i] = ((const float4*)ftab_g)[i];
    __syncthreads();
    const float2* ftab = (const float2*)smem;
    float d0v = hdr[0], rmaxv = hdr[1], invw = hdr[2], Stot = hdr[3];
    bool diag = (by == bx);

    float local = 0.f;
    int g = lane >> 4;
    int cl = lane & 15;
#pragma unroll
    for (int m = 0; m < 4; ++m) {
#pragma unroll
        for (int n = 0; n < 4; ++n) {
            floatx4 v = acc4[m][n];
            int gcl = wx * 64 + n * 16 + cl;
            float x2cv = x2c[gcl];
#pragma unroll
            for (int r = 0; r < 4; ++r) {
                int grl = wy * 64 + m * 16 + g * 4 + r;
                if (diag && grl == gcl) continue;
                float d = fmaxf(x2r[grl] + x2cv - 2.f * v[r], 0.f);
                if (d >= rmaxv) continue;
                if (d < d0v) {
                    local += fmaf(-d, (float)N, Stot);
                } else {
                    float tpos = (d - d0v) * invw;
                    int b = min((int)tpos, NBINS2 - 1);
                    float frac = tpos - (float)b;
                    float2 ab = ftab[b];
                    local += fmaf(frac, ab.y, ab.x);
                }
            }
        }
    }
    red[tid] = local;
    __syncthreads();
    for (int s2 = 128; s2 > 0; s2 >>= 1) {
        if (tid < s2) red[tid] += red[tid + s2];
        __syncthreads();
    }
    if (tid == 0) {
        float wt = diag ? 1.f : 2.f;
        pp[bid] = wt * red[0];
    }
}

// ---------------- finalize: reduce 528 partials + combine ----------------
__global__ __launch_bounds__(256) void finalize_kernel(const double* __restrict__ accd,
                                                       const float* __restrict__ pp,
                                                       float* __restrict__ out) {
    __shared__ double wsum[4];
    int t = threadIdx.x;
    double s = 0.0;
    for (int i = t; i < NPUSHBLK; i += 256) s += (double)pp[i];
#pragma unroll
    for (int off = 32; off > 0; off >>= 1) s += __shfl_xor(s, off, 64);
    if ((t & 63) == 0) wsum[t >> 6] = s;
    __syncthreads();
    if (t == 0) {
        double tot = wsum[0] + wsum[1] + wsum[2] + wsum[3];
        out[0] = (float)((accd[0] + tot - accd[2]) / (double)N);
    }
}

extern "C" void kernel_launch(void* const* d_in, const int* in_sizes, int n_in,
                              void* d_out, int out_size, void* d_ws, size_t ws_size,
                              hipStream_t stream) {
    const float* X = (const float*)d_in[0];
    const int* labels = (const int*)d_in[1];
    float* out = (float*)d_out;

    char* w = (char*)d_ws;
    double* accd   = (double*)w;                        // 64 B
    float* x2      = (float*)(w + 64);                  // 16 KB
    float* radii   = (float*)(w + 64 + 16384);          // 16 KB
    float* targetd = (float*)(w + 64 + 32768);          // 48 KB
    int* cnt       = (int*)(w + 64 + 81920);            // 256 B
    int* members   = (int*)(w + 64 + 82176);            // 64 KB
    float* hdr     = (float*)(w + 64 + 147712);         // 64 B
    float2* ftab_g = (float2*)(w + 64 + 147776);        // 32 KB
    float* pp      = (float*)(w + 64 + 180544);         // 528 floats -> 4 KB
    __hip_bfloat16* Xb = (__hip_bfloat16*)(w + 64 + 184640); // 2 MB
    size_t need_xb = 64 + 184640 + (size_t)N * DF * 2;
    int useXb = (ws_size >= need_xb) ? 1 : 0;

    hipLaunchKernelGGL(prep_kernel, dim3(1025), dim3(256), 0, stream,
                       X, labels, x2, Xb, cnt, members, accd, useXb);
    hipLaunchKernelGGL(knn_mfma_kernel, dim3(64), dim3(512), 0, stream,
                       X, x2, cnt, members, radii, targetd);
    hipLaunchKernelGGL(histo_ftab_kernel, dim3(1), dim3(1024), 0, stream,
                       radii, targetd, ftab_g, hdr, accd);
    if (useXb)
        hipLaunchKernelGGL(push_gemm_kernel<1>, dim3(NPUSHBLK), dim3(256), 0, stream,
                           X, Xb, x2, ftab_g, hdr, pp);
    else
        hipLaunchKernelGGL(push_gemm_kernel<0>, dim3(NPUSHBLK), dim3(256), 0, stream,
                           X, Xb, x2, ftab_g, hdr, pp);
    hipLaunchKernelGGL(finalize_kernel, dim3(1), dim3(256), 0, stream, accd, pp, out);
}